// Round 1
// baseline (609.806 us; speedup 1.0000x reference)
//
#include <hip/hip_runtime.h>

#define N_NODES 50000
#define N_EDGES 800000
#define E_TOT   (N_EDGES + N_NODES)
#define NUM_GRAPHS 64
#define NB_SCAN ((N_NODES + 1023) / 1024)   // 49 scan blocks

// ---------------- utility fills ----------------
__global__ void k_fill_i32(int* __restrict__ p, int n, int v) {
    int i = blockIdx.x * blockDim.x + threadIdx.x;
    if (i < n) p[i] = v;
}

// ---------------- degree histogram ----------------
__global__ void k_deg(const int* __restrict__ dst, int* __restrict__ deg) {
    int e = blockIdx.x * blockDim.x + threadIdx.x;
    if (e < N_EDGES) atomicAdd(&deg[dst[e]], 1);
}

// ---------------- 3-phase exclusive scan over deg -> row_start ----------------
__global__ __launch_bounds__(1024) void k_scan1(const int* __restrict__ deg,
                                                int* __restrict__ rs,
                                                int* __restrict__ bsum) {
    __shared__ int tmp[1024];
    int tid = threadIdx.x;
    int i = blockIdx.x * 1024 + tid;
    int v = (i < N_NODES) ? deg[i] : 0;
    tmp[tid] = v;
    __syncthreads();
    for (int off = 1; off < 1024; off <<= 1) {
        int add = (tid >= off) ? tmp[tid - off] : 0;
        __syncthreads();
        tmp[tid] += add;
        __syncthreads();
    }
    if (i < N_NODES) rs[i] = tmp[tid] - v;     // block-local exclusive
    if (tid == 1023) bsum[blockIdx.x] = tmp[1023];
}

__global__ void k_scan2(int* __restrict__ bsum) {
    int lane = threadIdx.x;                    // single wave of 64
    int v = (lane < NB_SCAN) ? bsum[lane] : 0;
    int inc = v;
    #pragma unroll
    for (int off = 1; off < 64; off <<= 1) {
        int u = __shfl_up(inc, off, 64);
        if (lane >= off) inc += u;
    }
    if (lane < NB_SCAN) bsum[lane] = inc - v;  // exclusive block offsets
}

__global__ __launch_bounds__(1024) void k_scan3(int* __restrict__ rs,
                                                const int* __restrict__ bsum,
                                                int* __restrict__ cursor,
                                                const int* __restrict__ deg,
                                                float* __restrict__ dinv) {
    int i = blockIdx.x * 1024 + threadIdx.x;
    if (i < N_NODES) {
        int r = rs[i] + bsum[blockIdx.x];
        rs[i] = r;
        cursor[i] = r;
        dinv[i] = rsqrtf((float)deg[i]);
    }
    if (i == 0) rs[N_NODES] = E_TOT;           // total is a compile-time constant
}

// ---------------- CSR scatter (edges + self loops) ----------------
__global__ void k_scatter(const int* __restrict__ ei, int* __restrict__ cursor,
                          int* __restrict__ csr) {
    int e = blockIdx.x * blockDim.x + threadIdx.x;
    if (e >= E_TOT) return;
    int s, d;
    if (e < N_EDGES) { s = ei[e]; d = ei[N_EDGES + e]; }
    else             { s = e - N_EDGES; d = s; }
    int p = atomicAdd(&cursor[d], 1);
    csr[p] = s;
}

// ---------------- GEMM: H[n, c0..c0+MT) = (X @ W)[n] * dinv[n] ----------------
// Register tile: NT(=4) nodes x 4 features per thread. W tile + transposed X tile in LDS.
template <int K, int M, int MT, int FTH, int NTH, int NT>
__global__ __launch_bounds__(FTH * NTH)
void k_gemm(const float* __restrict__ X, const float* __restrict__ W,
            const float* __restrict__ dinv, float* __restrict__ H) {
    constexpr int NODES = NTH * NT;
    constexpr int BLOCK = FTH * NTH;
    __shared__ float ws[K * MT];
    __shared__ float xs[K * NODES];            // xs[k*NODES + n] (transposed)
    const int tid = threadIdx.x;
    const int n0 = blockIdx.x * NODES;
    const int c0 = blockIdx.y * MT;

    for (int i = tid; i < K * MT / 4; i += BLOCK) {
        int k = i / (MT / 4), cv = i % (MT / 4);
        *(float4*)&ws[k * MT + cv * 4] = *(const float4*)&W[k * M + c0 + cv * 4];
    }
    constexpr int KV = K / 4;
    for (int i = tid; i < NODES * KV; i += BLOCK) {
        int r = i / KV, kv = i % KV;
        int node = n0 + r;
        float4 v = make_float4(0.f, 0.f, 0.f, 0.f);
        if (node < N_NODES) v = *(const float4*)&X[(size_t)node * K + kv * 4];
        xs[(kv * 4 + 0) * NODES + r] = v.x;
        xs[(kv * 4 + 1) * NODES + r] = v.y;
        xs[(kv * 4 + 2) * NODES + r] = v.z;
        xs[(kv * 4 + 3) * NODES + r] = v.w;
    }
    __syncthreads();

    const int ft = tid % FTH;
    const int nt = tid / FTH;
    float acc[NT][4];
    #pragma unroll
    for (int i = 0; i < NT; ++i) { acc[i][0] = acc[i][1] = acc[i][2] = acc[i][3] = 0.f; }

    #pragma unroll 4
    for (int k = 0; k < K; ++k) {
        float4 w = *(const float4*)&ws[k * MT + ft * 4];
        float4 xv = *(const float4*)&xs[k * NODES + nt * NT];
        float xa[4] = {xv.x, xv.y, xv.z, xv.w};
        #pragma unroll
        for (int j = 0; j < NT; ++j) {
            acc[j][0] += xa[j] * w.x;
            acc[j][1] += xa[j] * w.y;
            acc[j][2] += xa[j] * w.z;
            acc[j][3] += xa[j] * w.w;
        }
    }
    #pragma unroll
    for (int i = 0; i < NT; ++i) {
        int node = n0 + nt * NT + i;
        if (node < N_NODES) {
            float s = dinv[node];
            float4 o = make_float4(acc[i][0] * s, acc[i][1] * s, acc[i][2] * s, acc[i][3] * s);
            *(float4*)&H[(size_t)node * M + c0 + ft * 4] = o;
        }
    }
}

// ---------------- pull aggregation: OUT[n] = relu(dinv[n]*sum_e H[src_e] + b) ----------------
template <int F, bool POOL>
__global__ void k_agg(const float* __restrict__ H, const int* __restrict__ rs,
                      const int* __restrict__ csr, const float* __restrict__ dinv,
                      const float* __restrict__ bias, float* __restrict__ OUT,
                      const int* __restrict__ batch, float* __restrict__ gsum,
                      int* __restrict__ gcnt) {
    constexpr int FV = F / 4;
    int t = blockIdx.x * blockDim.x + threadIdx.x;
    int node = t / FV, c = t % FV;
    if (node >= N_NODES) return;
    int e0 = rs[node], e1 = rs[node + 1];
    float ax = 0.f, ay = 0.f, az = 0.f, aw = 0.f;
    for (int e = e0; e < e1; ++e) {
        int s = csr[e];
        float4 v = *(const float4*)&H[(size_t)s * F + c * 4];
        ax += v.x; ay += v.y; az += v.z; aw += v.w;
    }
    float d = dinv[node];
    float4 b = *(const float4*)&bias[c * 4];
    float ox = fmaxf(ax * d + b.x, 0.f);
    float oy = fmaxf(ay * d + b.y, 0.f);
    float oz = fmaxf(az * d + b.z, 0.f);
    float ow = fmaxf(aw * d + b.w, 0.f);
    if constexpr (POOL) {
        int g = batch[node];
        atomicAdd(&gsum[g * F + c * 4 + 0], ox);
        atomicAdd(&gsum[g * F + c * 4 + 1], oy);
        atomicAdd(&gsum[g * F + c * 4 + 2], oz);
        atomicAdd(&gsum[g * F + c * 4 + 3], ow);
        if (c == 0) atomicAdd(&gcnt[g], 1);
    } else {
        *(float4*)&OUT[(size_t)node * F + c * 4] = make_float4(ox, oy, oz, ow);
    }
}

__global__ void k_final(const float* __restrict__ gsum, const int* __restrict__ gcnt,
                        float* __restrict__ out) {
    int t = blockIdx.x * blockDim.x + threadIdx.x;
    if (t < NUM_GRAPHS * 32) {
        int g = t / 32;
        float c = fmaxf((float)gcnt[g], 1.0f);
        out[t] = gsum[t] / c;
    }
}

extern "C" void kernel_launch(void* const* d_in, const int* in_sizes, int n_in,
                              void* d_out, int out_size, void* d_ws, size_t ws_size,
                              hipStream_t stream) {
    const float* x     = (const float*)d_in[0];
    const int*   ei    = (const int*)d_in[1];
    const int*   batch = (const int*)d_in[2];
    const float* W1    = (const float*)d_in[3];
    const float* b1    = (const float*)d_in[4];
    const float* W2    = (const float*)d_in[5];
    const float* b2    = (const float*)d_in[6];
    const float* W3    = (const float*)d_in[7];
    const float* b3    = (const float*)d_in[8];
    float* out = (float*)d_out;

    char* ws = (char*)d_ws;
    size_t o = 0;
    auto alloc = [&](size_t bytes) {
        char* p = ws + o;
        o = (o + bytes + 255) & ~(size_t)255;
        return p;
    };
    float* bufA = (float*)alloc((size_t)N_NODES * 96 * 4);
    float* bufB = (float*)alloc((size_t)N_NODES * 96 * 4);
    int*   deg    = (int*)alloc((size_t)N_NODES * 4);
    float* dinv   = (float*)alloc((size_t)N_NODES * 4);
    int*   rs     = (int*)alloc((size_t)(N_NODES + 1) * 4);
    int*   cursor = (int*)alloc((size_t)N_NODES * 4);
    int*   csr    = (int*)alloc((size_t)E_TOT * 4);
    int*   bsum   = (int*)alloc(64 * 4);
    float* gsum   = (float*)alloc((size_t)NUM_GRAPHS * 32 * 4 + 64 * 4);
    int*   gcnt   = (int*)(gsum + NUM_GRAPHS * 32);

    // build normalization + CSR (by dst)
    hipLaunchKernelGGL(k_fill_i32, dim3((N_NODES + 255) / 256), dim3(256), 0, stream, deg, N_NODES, 1);
    hipLaunchKernelGGL(k_fill_i32, dim3(9), dim3(256), 0, stream, (int*)gsum, NUM_GRAPHS * 32 + 64, 0);
    hipLaunchKernelGGL(k_deg, dim3((N_EDGES + 255) / 256), dim3(256), 0, stream, ei + N_EDGES, deg);
    hipLaunchKernelGGL(k_scan1, dim3(NB_SCAN), dim3(1024), 0, stream, deg, rs, bsum);
    hipLaunchKernelGGL(k_scan2, dim3(1), dim3(64), 0, stream, bsum);
    hipLaunchKernelGGL(k_scan3, dim3(NB_SCAN), dim3(1024), 0, stream, rs, bsum, cursor, deg, dinv);
    hipLaunchKernelGGL(k_scatter, dim3((E_TOT + 255) / 256), dim3(256), 0, stream, ei, cursor, csr);

    // layer 1: K=128 -> M=96 (two 48-wide W tiles)
    hipLaunchKernelGGL((k_gemm<128, 96, 48, 12, 16, 4>), dim3((N_NODES + 63) / 64, 2), dim3(192), 0, stream,
                       x, W1, dinv, bufA);
    hipLaunchKernelGGL((k_agg<96, false>), dim3((N_NODES * 24 + 255) / 256), dim3(256), 0, stream,
                       bufA, rs, csr, dinv, b1, bufB, nullptr, nullptr, nullptr);
    // layer 2: K=96 -> M=48
    hipLaunchKernelGGL((k_gemm<96, 48, 48, 12, 16, 4>), dim3((N_NODES + 63) / 64, 1), dim3(192), 0, stream,
                       bufB, W2, dinv, bufA);
    hipLaunchKernelGGL((k_agg<48, false>), dim3((N_NODES * 12 + 255) / 256), dim3(256), 0, stream,
                       bufA, rs, csr, dinv, b2, bufB, nullptr, nullptr, nullptr);
    // layer 3: K=48 -> M=32, aggregation fused with mean-pool accumulation
    hipLaunchKernelGGL((k_gemm<48, 32, 32, 8, 24, 4>), dim3((N_NODES + 95) / 96, 1), dim3(192), 0, stream,
                       bufB, W3, dinv, bufA);
    hipLaunchKernelGGL((k_agg<32, true>), dim3((N_NODES * 8 + 255) / 256), dim3(256), 0, stream,
                       bufA, rs, csr, dinv, b3, nullptr, batch, gsum, gcnt);
    hipLaunchKernelGGL(k_final, dim3((NUM_GRAPHS * 32 + 255) / 256), dim3(256), 0, stream, gsum, gcnt, out);
}